// Round 2
// 30602.631 us; speedup vs baseline: 1.4091x; 1.4091x over previous
//
#include <hip/hip_runtime.h>
#include <stdint.h>

#define B_ 64
#define S_ 512
#define I_ 1024
#define H_ 1024

typedef __attribute__((ext_vector_type(8))) short bf16x8;
typedef __attribute__((ext_vector_type(4))) float f32x4;

// ---- workspace layout (bytes). All fp32 values carried as bf16 hi/lo planes.
#define BAR_OFF   0u                     // 4 KB: 4 group counters, 256B apart
#define BIAS_OFF  4096u                  // 16 KB fp32[4096] (bih+bhh)
#define XT_OFF    32768u                 // 2 x 128 KB bf16[64][1024] hi,lo
#define HT0_OFF   (XT_OFF + 262144u)
#define HT1_OFF   (HT0_OFF + 262144u)
#define QT_OFF    (1u << 20)             // 2 x 2 MB  Qt[n][k]=Q[k][n] hi,lo
#define RT_OFF    (5u << 20)
#define GT_OFF    (9u << 20)             // 2 x 16 MB Gt[n][k]={Wih|Whh}[k][n] hi,lo
#define APLANE    65536                  // activation plane stride (elements)
#define QPLANE    (1024 * 1024)          // Q/R plane stride (elements)
#define GPLANE    (4096 * 2048)          // G plane stride (elements)
#define GGATE     (1024 * 2048)          // Gt per-gate-quadrant stride (elements)

__device__ inline float bf2f(uint16_t u) {
    uint32_t v = ((uint32_t)u) << 16; float f; __builtin_memcpy(&f, &v, 4); return f;
}
__device__ inline uint16_t f2bf(float f) {
    uint32_t v; __builtin_memcpy(&v, &f, 4);
    v = (v + 0x7FFFu + ((v >> 16) & 1u)) >> 16;   // round-to-nearest-even
    return (uint16_t)v;
}
__device__ inline void f2hilo(float v, uint16_t& hi, uint16_t& lo) {
    hi = f2bf(v);
    lo = f2bf(v - bf2f(hi));
}
__device__ inline float sigmf(float x) { return 1.0f / (1.0f + __expf(-x)); }

// Coherent (agent-scope, sc1 = L1/L2-bypassing) 16B activation load, 2x8B relaxed atomics.
__device__ inline bf16x8 cload16(const uint16_t* p) {
    union { unsigned long long q[2]; bf16x8 v; } u;
    u.q[0] = __hip_atomic_load((const unsigned long long*)p,
                               __ATOMIC_RELAXED, __HIP_MEMORY_SCOPE_AGENT);
    u.q[1] = __hip_atomic_load((const unsigned long long*)p + 1,
                               __ATOMIC_RELAXED, __HIP_MEMORY_SCOPE_AGENT);
    return u.v;
}
// Coherent write-through 2B store (sc0 sc1): reaches the coherence point (L3),
// never leaves a dirty/stale line in the per-XCD L2. Tracked by vmcnt.
__device__ inline void cstore2(uint16_t* p, uint16_t v) {
    asm volatile("global_store_short %0, %1, off sc0 sc1"
                 :: "v"(p), "v"((uint32_t)v) : "memory");
}

// dst[n][k] = src[k][n] as bf16 hi/lo planes; src fp32 row-major [.,N]
__global__ __launch_bounds__(256)
void transpose_f32(const float* __restrict__ src, uint16_t* __restrict__ dstHi,
                   uint16_t* __restrict__ dstLo, int N, int dstStride, int dstColOff)
{
    __shared__ float tile[64][65];
    int k0 = blockIdx.x * 64;
    int n0 = blockIdx.y * 64;
    for (int i = threadIdx.x; i < 4096; i += 256) {
        int rr = i >> 6, cc = i & 63;
        tile[rr][cc] = src[(int64_t)(k0 + rr) * N + n0 + cc];
    }
    __syncthreads();
    for (int i = threadIdx.x; i < 4096; i += 256) {
        int rr = i >> 6, cc = i & 63;
        float v = tile[cc][rr];
        uint16_t hi, lo; f2hilo(v, hi, lo);
        int64_t o = (int64_t)(n0 + rr) * dstStride + dstColOff + k0 + cc;
        dstHi[o] = hi; dstLo[o] = lo;
    }
}

__global__ __launch_bounds__(256)
void bias_kernel(const float* __restrict__ a, const float* __restrict__ b,
                 float* __restrict__ o)
{
    int i = blockIdx.x * 256 + threadIdx.x;
    if (i < 4096) o[i] = a[i] + b[i];
}

// Persistent mogrifier-LSTM. 256 WGs = 4 row-groups (16 batch rows each,
// independent barrier domains) x 64 col-slices (16 cols). blk->(r,c) keeps a
// column's 4 row-WGs and adjacent slices on one XCD.
// Coherence: NO agent fences (they wbl2+inv the per-XCD L2 and evict the
// L2-resident weight slices every phase). Instead: activation exchange uses
// per-instruction coherent ops (sc1); weights use plain cached loads.
__global__ __launch_bounds__(256, 1)
void mog_lstm(const float* __restrict__ x,
              const float* __restrict__ h0,
              const float* __restrict__ c0,
              const uint16_t* __restrict__ Qt,   // hi plane; lo at +QPLANE
              const uint16_t* __restrict__ Rt,
              const uint16_t* __restrict__ Gt,   // hi plane; lo at +GPLANE
              const float*    __restrict__ biasf,
              uint16_t* __restrict__ xtb,        // hi plane; lo at +APLANE
              uint16_t* __restrict__ ht0b,
              uint16_t* __restrict__ ht1b,
              uint32_t* __restrict__ bar,
              float* __restrict__ out)
{
    const int tid  = threadIdx.x;
    const int lane = tid & 63;
    const int wave = tid >> 6;
    const int blk  = blockIdx.x;
    const int r    = (blk >> 3) & 3;             // row group 0..3
    const int c    = (blk & 7) * 8 + (blk >> 5); // col slice 0..63 (XCD-blocked)
    const int q4   = lane >> 4;
    const int cl   = lane & 15;
    const int kOff = q4 * 8;

    __shared__ float part[4][4][16][16];         // [wave][gate][row][col]
    __shared__ float Ct_s[16][16];
    __shared__ float xsh[16][16];                // fp32 shadow of own xt slice
    __shared__ float hsh[16][16];                // fp32 shadow of own ht slice

    uint32_t* cnt = bar + r * 64;
    uint32_t bt = 0;
    uint32_t dead = 0;                           // sticky: once a barrier times
                                                 // out, never wait again

    // Fence-free barrier: all cross-WG data stores are wave0's coherent
    // (write-through sc1) stores; tid0 (in wave0) orders them with a raw
    // vmcnt(0) before the relaxed counter bump. No cache maintenance executes.
    // Per-barrier 0.4s watchdog; sticky dead flag bounds worst-case stall.
    auto gbar = [&]() {
        bt += 64;
        __syncthreads();
        if (tid == 0) {
            asm volatile("s_waitcnt vmcnt(0)" ::: "memory");
            __hip_atomic_fetch_add(cnt, 1u, __ATOMIC_RELAXED, __HIP_MEMORY_SCOPE_AGENT);
            if (!dead) {
                const uint64_t tw = __builtin_amdgcn_s_memrealtime();
                while (__hip_atomic_load(cnt, __ATOMIC_RELAXED, __HIP_MEMORY_SCOPE_AGENT) < bt) {
                    __builtin_amdgcn_s_sleep(2);
                    if (__builtin_amdgcn_s_memrealtime() - tw > 40000000ull) { // ~0.4s
                        dead = 1; break;
                    }
                }
            }
            asm volatile("" ::: "memory");
        }
        __syncthreads();
    };

    // u = A(rows 16r..) @ Wt(rows 16c..)^T, K=1024 split over 4 waves, split-bf16;
    // then new = 2*sigmoid(u) * old. old comes from the fp32 LDS shadow `sh`
    // (own slice, written by self last phase) or from global x (gF). New value
    // is published coherently (hi/lo bf16 planes) and kept in `sh`.
    auto mogp = [&](const uint16_t* __restrict__ Ahi, const uint16_t* __restrict__ Whi,
                    const float* gF, int64_t gFs, uint16_t* gHi, float (*sh)[16]) {
        const int64_t aoff = (int64_t)(r * 16 + cl) * 1024 + wave * 256 + kOff;
        const int64_t boff = (int64_t)(c * 16 + cl) * 1024 + wave * 256 + kOff;
        const uint16_t* ah = Ahi + aoff;
        const uint16_t* al = Ahi + APLANE + aoff;
        const uint16_t* bh = Whi + boff;
        const uint16_t* bl = Whi + QPLANE + boff;
        f32x4 acc = {0.f, 0.f, 0.f, 0.f};
#pragma unroll
        for (int k = 0; k < 256; k += 32) {
            bf16x8 vah = cload16(ah + k);
            bf16x8 val = cload16(al + k);
            bf16x8 vbh = *(const bf16x8*)(bh + k);
            bf16x8 vbl = *(const bf16x8*)(bl + k);
            acc = __builtin_amdgcn_mfma_f32_16x16x32_bf16(vah, vbh, acc, 0, 0, 0);
            acc = __builtin_amdgcn_mfma_f32_16x16x32_bf16(vah, vbl, acc, 0, 0, 0);
            acc = __builtin_amdgcn_mfma_f32_16x16x32_bf16(val, vbh, acc, 0, 0, 0);
        }
#pragma unroll
        for (int i = 0; i < 4; ++i) part[wave][0][q4 * 4 + i][cl] = acc[i];
        __syncthreads();
        if (wave == 0) {
#pragma unroll
            for (int i = 0; i < 4; ++i) {
                int row = q4 * 4 + i;
                float u = part[0][0][row][cl] + part[1][0][row][cl]
                        + part[2][0][row][cl] + part[3][0][row][cl];
                float gm = 2.0f * sigmf(u);
                float oldv = gF ? __builtin_nontemporal_load(gF + (int64_t)row * gFs + cl)
                                : sh[row][cl];
                float nv = gm * oldv;
                sh[row][cl] = nv;
                uint16_t hi, lo; f2hilo(nv, hi, lo);
                cstore2(gHi + row * 1024 + cl, hi);
                cstore2(gHi + APLANE + row * 1024 + cl, lo);
            }
        }
    };

    // init: ht0 = h0 (hi/lo planes + fp32 shadow), Ct_s = c0, own slice
    if (wave == 0) {
#pragma unroll
        for (int i = 0; i < 4; ++i) {
            int row = q4 * 4 + i;
            int grow = r * 16 + row, gcol = c * 16 + cl;
            float hv = h0[grow * 1024 + gcol];
            uint16_t hi, lo; f2hilo(hv, hi, lo);
            cstore2(ht0b + grow * 1024 + gcol, hi);
            cstore2(ht0b + APLANE + grow * 1024 + gcol, lo);
            hsh[row][cl] = hv;
            Ct_s[row][cl] = c0[grow * 1024 + gcol];
        }
    }
    gbar();

    for (int t = 0; t < S_; ++t) {
        const int p = t & 1;
        uint16_t* htp = p ? ht1b : ht0b;   // ht for this step
        uint16_t* htn = p ? ht0b : ht1b;   // ht_new parity
        uint16_t* xsl = xtb + (r * 16) * 1024 + c * 16;
        uint16_t* hsl = htp + (r * 16) * 1024 + c * 16;
        const float* xsrc = x + (int64_t)(r * 16) * (S_ * I_) + (int64_t)t * I_ + c * 16;

        mogp(htp, Qt, xsrc, (int64_t)S_ * I_, xsl, xsh); gbar(); // xt1 = 2s(ht0@Q)*x_t
        mogp(xtb, Rt, nullptr, 0, hsl, hsh);             gbar(); // ht1 = 2s(xt1@R)*ht0
        mogp(htp, Qt, nullptr, 0, xsl, xsh);             gbar(); // xt2 = 2s(ht1@Q)*xt1
        mogp(xtb, Rt, nullptr, 0, hsl, hsh);             gbar(); // ht2 = 2s(xt2@R)*ht1

        // ---- P5: gates = [xt2|ht2] @ Gt^T + bias, K split across waves,
        // each wave computes all 4 gate quadrants (no A duplication) ----
        {
            const int64_t arow = (int64_t)(r * 16 + cl) * 1024 + wave * 256 + kOff;
            const uint16_t* axh = xtb + arow;
            const uint16_t* axl = xtb + APLANE + arow;
            const uint16_t* ahh = htp + arow;
            const uint16_t* ahl = htp + APLANE + arow;
            const uint16_t* gB = Gt + (int64_t)(c * 16 + cl) * 2048 + wave * 256 + kOff;
            f32x4 accg[4] = {{0.f,0.f,0.f,0.f},{0.f,0.f,0.f,0.f},
                             {0.f,0.f,0.f,0.f},{0.f,0.f,0.f,0.f}};
#pragma unroll 4
            for (int k = 0; k < 256; k += 32) {
                bf16x8 vxh = cload16(axh + k);
                bf16x8 vxl = cload16(axl + k);
                bf16x8 vhh = cload16(ahh + k);
                bf16x8 vhl = cload16(ahl + k);
#pragma unroll
                for (int g = 0; g < 4; ++g) {
                    const uint16_t* bx = gB + (int64_t)g * GGATE + k;
                    bf16x8 bxh = *(const bf16x8*)(bx);
                    bf16x8 bxl = *(const bf16x8*)(bx + GPLANE);
                    f32x4 a = accg[g];
                    a = __builtin_amdgcn_mfma_f32_16x16x32_bf16(vxh, bxh, a, 0, 0, 0);
                    a = __builtin_amdgcn_mfma_f32_16x16x32_bf16(vxh, bxl, a, 0, 0, 0);
                    a = __builtin_amdgcn_mfma_f32_16x16x32_bf16(vxl, bxh, a, 0, 0, 0);
                    bf16x8 bhh2 = *(const bf16x8*)(bx + 1024);
                    bf16x8 bhl2 = *(const bf16x8*)(bx + GPLANE + 1024);
                    a = __builtin_amdgcn_mfma_f32_16x16x32_bf16(vhh, bhh2, a, 0, 0, 0);
                    a = __builtin_amdgcn_mfma_f32_16x16x32_bf16(vhh, bhl2, a, 0, 0, 0);
                    a = __builtin_amdgcn_mfma_f32_16x16x32_bf16(vhl, bhh2, a, 0, 0, 0);
                    accg[g] = a;
                }
            }
#pragma unroll
            for (int g = 0; g < 4; ++g)
#pragma unroll
                for (int i = 0; i < 4; ++i)
                    part[wave][g][q4 * 4 + i][cl] = accg[g][i];
            __syncthreads();
            if (wave == 0) {
                const int gcol = c * 16 + cl;
                const float bi = biasf[gcol];
                const float bf = biasf[1024 + gcol];
                const float bg = biasf[2048 + gcol];
                const float bo = biasf[3072 + gcol];
#pragma unroll
                for (int i = 0; i < 4; ++i) {
                    int row = q4 * 4 + i;
                    float gi = part[0][0][row][cl] + part[1][0][row][cl]
                             + part[2][0][row][cl] + part[3][0][row][cl] + bi;
                    float gf = part[0][1][row][cl] + part[1][1][row][cl]
                             + part[2][1][row][cl] + part[3][1][row][cl] + bf;
                    float gg = part[0][2][row][cl] + part[1][2][row][cl]
                             + part[2][2][row][cl] + part[3][2][row][cl] + bg;
                    float go = part[0][3][row][cl] + part[1][3][row][cl]
                             + part[2][3][row][cl] + part[3][3][row][cl] + bo;
                    float ii = sigmf(gi), ff = sigmf(gf);
                    float g2 = tanhf(gg), oo = sigmf(go);
                    float Cn = ff * Ct_s[row][cl] + ii * g2;
                    float hh = oo * tanhf(Cn);
                    Ct_s[row][cl] = Cn;
                    hsh[row][cl] = hh;
                    int grow = r * 16 + row;
                    uint16_t hi, lo; f2hilo(hh, hi, lo);
                    cstore2(htn + grow * 1024 + gcol, hi);
                    cstore2(htn + APLANE + grow * 1024 + gcol, lo);
                    __builtin_nontemporal_store(hh,
                        out + (int64_t)grow * (S_ * H_) + (int64_t)t * H_ + gcol);
                    if (t == S_ - 1)
                        out[(int64_t)B_ * S_ * H_ + grow * H_ + gcol] = hh;
                }
            }
        }
        gbar();
    }

    if (wave == 0) {
#pragma unroll
        for (int i = 0; i < 4; ++i) {
            int row = q4 * 4 + i;
            int grow = r * 16 + row, gcol = c * 16 + cl;
            out[(int64_t)B_ * S_ * H_ + (int64_t)B_ * H_ + grow * H_ + gcol] = Ct_s[row][cl];
        }
    }
}

extern "C" void kernel_launch(void* const* d_in, const int* in_sizes, int n_in,
                              void* d_out, int out_size, void* d_ws, size_t ws_size,
                              hipStream_t stream)
{
    (void)in_sizes; (void)n_in; (void)out_size; (void)ws_size;
    const float* x   = (const float*)d_in[0];
    const float* h0  = (const float*)d_in[1];
    const float* c0  = (const float*)d_in[2];
    const float* Wih = (const float*)d_in[3];
    const float* Whh = (const float*)d_in[4];
    const float* bih = (const float*)d_in[5];
    const float* bhh = (const float*)d_in[6];
    const float* Q   = (const float*)d_in[7];
    const float* R   = (const float*)d_in[8];

    char* ws = (char*)d_ws;
    uint32_t* bar   = (uint32_t*)(ws + BAR_OFF);
    float*    biasf = (float*)(ws + BIAS_OFF);
    uint16_t* xtb   = (uint16_t*)(ws + XT_OFF);
    uint16_t* ht0b  = (uint16_t*)(ws + HT0_OFF);
    uint16_t* ht1b  = (uint16_t*)(ws + HT1_OFF);
    uint16_t* Qt    = (uint16_t*)(ws + QT_OFF);
    uint16_t* Rt    = (uint16_t*)(ws + RT_OFF);
    uint16_t* Gt    = (uint16_t*)(ws + GT_OFF);

    (void)hipMemsetAsync(ws + BAR_OFF, 0, 4096, stream);
    bias_kernel<<<16, 256, 0, stream>>>(bih, bhh, biasf);
    transpose_f32<<<dim3(16, 16), 256, 0, stream>>>(Q,   Qt, Qt + QPLANE, 1024, 1024, 0);
    transpose_f32<<<dim3(16, 16), 256, 0, stream>>>(R,   Rt, Rt + QPLANE, 1024, 1024, 0);
    transpose_f32<<<dim3(16, 64), 256, 0, stream>>>(Wih, Gt, Gt + GPLANE, 4096, 2048, 0);
    transpose_f32<<<dim3(16, 64), 256, 0, stream>>>(Whh, Gt, Gt + GPLANE, 4096, 2048, 1024);
    mog_lstm<<<256, 256, 0, stream>>>(x, h0, c0, Qt, Rt, Gt, biasf,
                                      xtb, ht0b, ht1b, bar, (float*)d_out);
}

// Round 5
// 28091.754 us; speedup vs baseline: 1.5350x; 1.0894x over previous
//
#include <hip/hip_runtime.h>
#include <stdint.h>

#define B_ 64
#define S_ 512
#define I_ 1024
#define H_ 1024

typedef __attribute__((ext_vector_type(8))) short bf16x8;
typedef __attribute__((ext_vector_type(4))) float f32x4;
typedef unsigned long long u64;

// ---- workspace layout (bytes). All fp32 values carried as bf16 hi/lo planes.
#define BAR_OFF   0u                     // 4 KB: 4 group counters, 256B apart
#define BIAS_OFF  4096u                  // 16 KB fp32[4096] (bih+bhh)
#define XT_OFF    32768u                 // 2 x 128 KB bf16[64][1024] hi,lo
#define HT0_OFF   (XT_OFF + 262144u)
#define HT1_OFF   (HT0_OFF + 262144u)
#define QT_OFF    (1u << 20)             // 2 x 2 MB  Qt[n][k]=Q[k][n] hi,lo
#define RT_OFF    (5u << 20)
#define GT_OFF    (9u << 20)             // 2 x 16 MB Gt[n][k]={Wih|Whh}[k][n] hi,lo
#define APLANE    65536                  // activation plane stride (elements)
#define QPLANE    (1024 * 1024)          // Q/R plane stride (elements)
#define GPLANE    (4096 * 2048)          // G plane stride (elements)
#define GGATE     (1024 * 2048)          // Gt per-gate-quadrant stride (elements)

__device__ inline float bf2f(uint16_t u) {
    uint32_t v = ((uint32_t)u) << 16; float f; __builtin_memcpy(&f, &v, 4); return f;
}
__device__ inline uint16_t f2bf(float f) {
    uint32_t v; __builtin_memcpy(&v, &f, 4);
    v = (v + 0x7FFFu + ((v >> 16) & 1u)) >> 16;   // round-to-nearest-even
    return (uint16_t)v;
}
__device__ inline void f2hilo(float v, uint16_t& hi, uint16_t& lo) {
    hi = f2bf(v);
    lo = f2bf(v - bf2f(hi));
}
__device__ inline float sigmf(float x) { return 1.0f / (1.0f + __expf(-x)); }

// Coherent (agent-scope, sc1 = bypass per-XCD L2) 8B relaxed atomic load.
// Proven in round 2 (passed numerics at 30.6 ms).
__device__ inline u64 cload8(const uint16_t* p) {
    return __hip_atomic_load((const u64*)p, __ATOMIC_RELAXED, __HIP_MEMORY_SCOPE_AGENT);
}
// Coherent write-through 2B store (sc0 sc1). Proven in round 2.
__device__ inline void cstore2(uint16_t* p, uint16_t v) {
    asm volatile("global_store_short %0, %1, off sc0 sc1"
                 :: "v"(p), "v"((uint32_t)v) : "memory");
}

union U2 { u64 q[2]; bf16x8 v; };

// dst[n][k] = src[k][n] as bf16 hi/lo planes; src fp32 row-major [.,N]
__global__ __launch_bounds__(256)
void transpose_f32(const float* __restrict__ src, uint16_t* __restrict__ dstHi,
                   uint16_t* __restrict__ dstLo, int N, int dstStride, int dstColOff)
{
    __shared__ float tile[64][65];
    int k0 = blockIdx.x * 64;
    int n0 = blockIdx.y * 64;
    for (int i = threadIdx.x; i < 4096; i += 256) {
        int rr = i >> 6, cc = i & 63;
        tile[rr][cc] = src[(int64_t)(k0 + rr) * N + n0 + cc];
    }
    __syncthreads();
    for (int i = threadIdx.x; i < 4096; i += 256) {
        int rr = i >> 6, cc = i & 63;
        float v = tile[cc][rr];
        uint16_t hi, lo; f2hilo(v, hi, lo);
        int64_t o = (int64_t)(n0 + rr) * dstStride + dstColOff + k0 + cc;
        dstHi[o] = hi; dstLo[o] = lo;
    }
}

__global__ __launch_bounds__(256)
void bias_kernel(const float* __restrict__ a, const float* __restrict__ b,
                 float* __restrict__ o)
{
    int i = blockIdx.x * 256 + threadIdx.x;
    if (i < 4096) o[i] = a[i] + b[i];
}

// Persistent mogrifier-LSTM. 256 WGs = 4 row-groups (16 batch rows each,
// independent barrier domains) x 64 col-slices (16 cols). blk->(r,c) keeps a
// column's 4 row-WGs and adjacent slices on one XCD (weight L2 locality).
// Sync: round-2-PROVEN counter barrier (no fences -> no L2 wbl2/inv, weights
// stay L2-resident). Producer visibility: sc0sc1 write-through stores drained
// by __syncthreads' implicit vmcnt(0) before tid0 bumps the counter.
// A-operands: per phase, each wave bulk-issues ALL its A-fragment loads
// (32 x 8B relaxed agent atomics = one L3 round-trip) into registers, then
// runs the MFMA loop purely from regs + L2-cached weight loads.
__global__ __launch_bounds__(256, 1)
void mog_lstm(const float* __restrict__ x,
              const float* __restrict__ h0,
              const float* __restrict__ c0,
              const uint16_t* __restrict__ Qt,   // hi plane; lo at +QPLANE
              const uint16_t* __restrict__ Rt,
              const uint16_t* __restrict__ Gt,   // hi plane; lo at +GPLANE
              const float*    __restrict__ biasf,
              uint16_t* __restrict__ xtb,        // hi plane; lo at +APLANE
              uint16_t* __restrict__ ht0b,
              uint16_t* __restrict__ ht1b,
              uint32_t* __restrict__ bar,
              float* __restrict__ out)
{
    const int tid  = threadIdx.x;
    const int lane = tid & 63;
    const int wave = tid >> 6;
    const int blk  = blockIdx.x;
    const int r    = (blk >> 3) & 3;             // row group 0..3
    const int c    = (blk & 7) * 8 + (blk >> 5); // col slice 0..63 (XCD-blocked)
    const int q4   = lane >> 4;
    const int cl   = lane & 15;
    const int kOff = q4 * 8;
    // epilogue row/col mapping (each wave owns 4 rows of the 16x16 slice)
    const int erow = wave * 4 + q4;
    const int ecol = cl;

    __shared__ float part[4][4][16][16];         // [wave][gate][row][col]
    __shared__ float Ct_s[16][16];
    __shared__ float xsh[16][16];                // fp32 shadow of own xt slice
    __shared__ float hsh[16][16];                // fp32 shadow of own ht slice

    uint32_t* cnt = bar + r * 64;
    uint32_t bt = 0;
    uint32_t dead = 0;                           // sticky watchdog flag

    // Round-2-proven fence-free barrier. __syncthreads drains every thread's
    // stores (compiler emits s_waitcnt vmcnt(0) before s_barrier), so by the
    // time tid0 adds, this WG's coherent stores are at the coherence point.
    auto gbar = [&]() {
        bt += 64;
        __syncthreads();
        if (tid == 0) {
            __hip_atomic_fetch_add(cnt, 1u, __ATOMIC_RELAXED, __HIP_MEMORY_SCOPE_AGENT);
            if (!dead) {
                const uint64_t tw = __builtin_amdgcn_s_memrealtime();
                while (__hip_atomic_load(cnt, __ATOMIC_RELAXED, __HIP_MEMORY_SCOPE_AGENT) < bt) {
                    __builtin_amdgcn_s_sleep(2);
                    if (__builtin_amdgcn_s_memrealtime() - tw > 40000000ull) { // ~0.4s
                        dead = 1; break;
                    }
                }
            }
            asm volatile("" ::: "memory");
        }
        __syncthreads();
    };

    // bulk A-fragment load: this wave's 16 rows x its K-quarter, hi+lo planes.
    // av[4*k8 + {0,1}] = hi 16B, av[4*k8 + {2,3}] = lo 16B.
    auto aload = [&](u64* av, const uint16_t* Abase) {
        const int64_t aoff = (int64_t)(r * 16 + cl) * 1024 + wave * 256 + kOff;
#pragma unroll
        for (int k8 = 0; k8 < 8; ++k8) {
            const uint16_t* ph = Abase + aoff + k8 * 32;
            const uint16_t* pl = Abase + APLANE + aoff + k8 * 32;
            av[4 * k8 + 0] = cload8(ph);
            av[4 * k8 + 1] = cload8(ph + 4);
            av[4 * k8 + 2] = cload8(pl);
            av[4 * k8 + 3] = cload8(pl + 4);
        }
    };

    // ---- mog phase: u = A @ Wt^T (K=1024 over 4 waves, split-bf16 3-MFMA),
    // new = 2*sigmoid(u)*old; old from LDS shadow (or global x for P1).
    auto mogp = [&](const uint16_t* Abase, const uint16_t* Whi,
                    const float* gF, int64_t gFs, uint16_t* gSlice,
                    float (*sh)[16]) {
        u64 av[32];
        aload(av, Abase);                          // one burst, all in flight
        {
            const int64_t boff = (int64_t)(c * 16 + cl) * 1024 + wave * 256 + kOff;
            const uint16_t* bh = Whi + boff;
            const uint16_t* bl = Whi + QPLANE + boff;
            f32x4 acc = {0.f, 0.f, 0.f, 0.f};
#pragma unroll
            for (int k8 = 0; k8 < 8; ++k8) {
                U2 uh, ul;
                uh.q[0] = av[4 * k8 + 0]; uh.q[1] = av[4 * k8 + 1];
                ul.q[0] = av[4 * k8 + 2]; ul.q[1] = av[4 * k8 + 3];
                bf16x8 vbh = *(const bf16x8*)(bh + k8 * 32);
                bf16x8 vbl = *(const bf16x8*)(bl + k8 * 32);
                acc = __builtin_amdgcn_mfma_f32_16x16x32_bf16(uh.v, vbh, acc, 0, 0, 0);
                acc = __builtin_amdgcn_mfma_f32_16x16x32_bf16(uh.v, vbl, acc, 0, 0, 0);
                acc = __builtin_amdgcn_mfma_f32_16x16x32_bf16(ul.v, vbh, acc, 0, 0, 0);
            }
#pragma unroll
            for (int i = 0; i < 4; ++i) part[wave][0][q4 * 4 + i][cl] = acc[i];
        }
        __syncthreads();
        {   // epilogue spread over 4 waves (4 rows each)
            float u = part[0][0][erow][ecol] + part[1][0][erow][ecol]
                    + part[2][0][erow][ecol] + part[3][0][erow][ecol];
            float gm = 2.0f * sigmf(u);
            float oldv = gF ? __builtin_nontemporal_load(gF + (int64_t)erow * gFs + ecol)
                            : sh[erow][ecol];
            float nv = gm * oldv;
            sh[erow][ecol] = nv;
            uint16_t hi, lo; f2hilo(nv, hi, lo);
            cstore2(gSlice + erow * 1024 + ecol, hi);
            cstore2(gSlice + APLANE + erow * 1024 + ecol, lo);
        }
    };

    // ---- init: ht0 = h0 (hi/lo + shadow), Ct_s = c0, own slice ----
    {
        int grow = r * 16 + erow, gcol = c * 16 + ecol;
        float hv = h0[grow * 1024 + gcol];
        uint16_t hi, lo; f2hilo(hv, hi, lo);
        cstore2(ht0b + grow * 1024 + gcol, hi);
        cstore2(ht0b + APLANE + grow * 1024 + gcol, lo);
        hsh[erow][ecol] = hv;
        Ct_s[erow][ecol] = c0[grow * 1024 + gcol];
    }
    gbar();

    // hoisted P5 per-thread constants
    const int   gcol5 = c * 16 + ecol;
    const float bi5 = biasf[gcol5];
    const float bf5 = biasf[1024 + gcol5];
    const float bg5 = biasf[2048 + gcol5];
    const float bo5 = biasf[3072 + gcol5];

    for (int t = 0; t < S_; ++t) {
        const int p = t & 1;
        uint16_t* htp = p ? ht1b : ht0b;   // ht for this step
        uint16_t* htn = p ? ht0b : ht1b;   // ht_new parity
        uint16_t* xsl = xtb + (r * 16) * 1024 + c * 16;
        uint16_t* hsl = htp + (r * 16) * 1024 + c * 16;
        const float* xsrc = x + (int64_t)(r * 16) * (S_ * I_) + (int64_t)t * I_ + c * 16;

        mogp(htp, Qt, xsrc, (int64_t)S_ * I_, xsl, xsh); gbar(); // xt1 = 2s(ht0@Q)*x_t
        mogp(xtb, Rt, nullptr, 0, hsl, hsh);             gbar(); // ht1 = 2s(xt1@R)*ht0
        mogp(htp, Qt, nullptr, 0, xsl, xsh);             gbar(); // xt2 = 2s(ht1@Q)*xt1
        mogp(xtb, Rt, nullptr, 0, hsl, hsh);             gbar(); // ht2 = 2s(xt2@R)*ht1

        // ---- P5: gates = [xt2|ht2] @ Gt^T + bias; K split across waves;
        // both A-slabs bulk-loaded to regs up front (x burst + h burst).
        {
            u64 xa[32], ha[32];
            aload(xa, xtb);                 // xt2 fragments
            aload(ha, htp);                 // ht2 fragments (fly during x-MFMAs)
            const uint16_t* gB = Gt + (int64_t)(c * 16 + cl) * 2048 + wave * 256 + kOff;
            f32x4 accg[4] = {{0.f,0.f,0.f,0.f},{0.f,0.f,0.f,0.f},
                             {0.f,0.f,0.f,0.f},{0.f,0.f,0.f,0.f}};
#pragma unroll
            for (int k8 = 0; k8 < 8; ++k8) {
                U2 xh, xl, hh, hl;
                xh.q[0] = xa[4 * k8 + 0]; xh.q[1] = xa[4 * k8 + 1];
                xl.q[0] = xa[4 * k8 + 2]; xl.q[1] = xa[4 * k8 + 3];
                hh.q[0] = ha[4 * k8 + 0]; hh.q[1] = ha[4 * k8 + 1];
                hl.q[0] = ha[4 * k8 + 2]; hl.q[1] = ha[4 * k8 + 3];
#pragma unroll
                for (int g = 0; g < 4; ++g) {
                    const uint16_t* bx = gB + (int64_t)g * GGATE + k8 * 32;
                    bf16x8 bxh = *(const bf16x8*)(bx);
                    bf16x8 bxl = *(const bf16x8*)(bx + GPLANE);
                    f32x4 a = accg[g];
                    a = __builtin_amdgcn_mfma_f32_16x16x32_bf16(xh.v, bxh, a, 0, 0, 0);
                    a = __builtin_amdgcn_mfma_f32_16x16x32_bf16(xh.v, bxl, a, 0, 0, 0);
                    a = __builtin_amdgcn_mfma_f32_16x16x32_bf16(xl.v, bxh, a, 0, 0, 0);
                    bf16x8 bhh2 = *(const bf16x8*)(bx + 1024);
                    bf16x8 bhl2 = *(const bf16x8*)(bx + GPLANE + 1024);
                    a = __builtin_amdgcn_mfma_f32_16x16x32_bf16(hh.v, bhh2, a, 0, 0, 0);
                    a = __builtin_amdgcn_mfma_f32_16x16x32_bf16(hh.v, bhl2, a, 0, 0, 0);
                    a = __builtin_amdgcn_mfma_f32_16x16x32_bf16(hl.v, bhh2, a, 0, 0, 0);
                    accg[g] = a;
                }
            }
#pragma unroll
            for (int g = 0; g < 4; ++g)
#pragma unroll
                for (int i = 0; i < 4; ++i)
                    part[wave][g][q4 * 4 + i][cl] = accg[g][i];
        }
        __syncthreads();
        {   // LSTM cell, spread over 4 waves
            float gi = part[0][0][erow][ecol] + part[1][0][erow][ecol]
                     + part[2][0][erow][ecol] + part[3][0][erow][ecol] + bi5;
            float gf = part[0][1][erow][ecol] + part[1][1][erow][ecol]
                     + part[2][1][erow][ecol] + part[3][1][erow][ecol] + bf5;
            float gg = part[0][2][erow][ecol] + part[1][2][erow][ecol]
                     + part[2][2][erow][ecol] + part[3][2][erow][ecol] + bg5;
            float go = part[0][3][erow][ecol] + part[1][3][erow][ecol]
                     + part[2][3][erow][ecol] + part[3][3][erow][ecol] + bo5;
            float ii = sigmf(gi), ff = sigmf(gf);
            float g2 = tanhf(gg), oo = sigmf(go);
            float Cn = ff * Ct_s[erow][ecol] + ii * g2;
            float hh = oo * tanhf(Cn);
            Ct_s[erow][ecol] = Cn;
            hsh[erow][ecol] = hh;
            int grow = r * 16 + erow;
            uint16_t hi, lo; f2hilo(hh, hi, lo);
            cstore2(htn + grow * 1024 + gcol5, hi);
            cstore2(htn + APLANE + grow * 1024 + gcol5, lo);
            __builtin_nontemporal_store(hh,
                out + (int64_t)grow * (S_ * H_) + (int64_t)t * H_ + gcol5);
            if (t == S_ - 1)
                out[(int64_t)B_ * S_ * H_ + grow * H_ + gcol5] = hh;
        }
        gbar();
    }

    {   // final cell state
        int grow = r * 16 + erow;
        out[(int64_t)B_ * S_ * H_ + (int64_t)B_ * H_ + grow * H_ + gcol5] = Ct_s[erow][ecol];
    }
}

extern "C" void kernel_launch(void* const* d_in, const int* in_sizes, int n_in,
                              void* d_out, int out_size, void* d_ws, size_t ws_size,
                              hipStream_t stream)
{
    (void)in_sizes; (void)n_in; (void)out_size; (void)ws_size;
    const float* x   = (const float*)d_in[0];
    const float* h0  = (const float*)d_in[1];
    const float* c0  = (const float*)d_in[2];
    const float* Wih = (const float*)d_in[3];
    const float* Whh = (const float*)d_in[4];
    const float* bih = (const float*)d_in[5];
    const float* bhh = (const float*)d_in[6];
    const float* Q   = (const float*)d_in[7];
    const float* R   = (const float*)d_in[8];

    char* ws = (char*)d_ws;
    uint32_t* bar   = (uint32_t*)(ws + BAR_OFF);
    float*    biasf = (float*)(ws + BIAS_OFF);
    uint16_t* xtb   = (uint16_t*)(ws + XT_OFF);
    uint16_t* ht0b  = (uint16_t*)(ws + HT0_OFF);
    uint16_t* ht1b  = (uint16_t*)(ws + HT1_OFF);
    uint16_t* Qt    = (uint16_t*)(ws + QT_OFF);
    uint16_t* Rt    = (uint16_t*)(ws + RT_OFF);
    uint16_t* Gt    = (uint16_t*)(ws + GT_OFF);

    (void)hipMemsetAsync(ws + BAR_OFF, 0, 4096, stream);
    bias_kernel<<<16, 256, 0, stream>>>(bih, bhh, biasf);
    transpose_f32<<<dim3(16, 16), 256, 0, stream>>>(Q,   Qt, Qt + QPLANE, 1024, 1024, 0);
    transpose_f32<<<dim3(16, 16), 256, 0, stream>>>(R,   Rt, Rt + QPLANE, 1024, 1024, 0);
    transpose_f32<<<dim3(16, 64), 256, 0, stream>>>(Wih, Gt, Gt + GPLANE, 4096, 2048, 0);
    transpose_f32<<<dim3(16, 64), 256, 0, stream>>>(Whh, Gt, Gt + GPLANE, 4096, 2048, 1024);
    mog_lstm<<<256, 256, 0, stream>>>(x, h0, c0, Qt, Rt, Gt, biasf,
                                      xtb, ht0b, ht1b, bar, (float*)d_out);
}